// Round 2
// baseline (1107.282 us; speedup 1.0000x reference)
//
#include <hip/hip_runtime.h>
#include <hip/hip_cooperative_groups.h>
#include <math.h>

namespace cg = cooperative_groups;

// ---------------------------------------------------------------------------
// Round 1: 64 blocks x 1024 threads (16 waves = 4/SIMD for latency hiding).
// Block owns 8 batch rows. Thread (s = t>>8, hh = t&255) computes the partial
// gate dot-products for hidden index hh over K-slice [64s, 64s+64).
// y broadcast via v_readlane from per-lane slice registers (lane l of a
// slice-s wave holds y[64s+l][8 rows]). Partial-K sums combined through LDS;
// s==0 threads apply bias + nonlinearity and store k into LDS k-history.
// L2 W traffic halves vs round 0 (64 blocks x 786KB/eval); 4 waves/SIMD
// hide L2 latency. All controller math fp32, same op order as round 0.
//
// Dynamic LDS (floats):
//   [0,18432)        pbuf[3][24][256]  (partial sums, s=1..3; aliased as xl at init)
//   [18432,32768)    k_lds[7][8][256]  (k-history, [stage][row][hidden])
//   [32768,34816)    y_lds[8][256]     (committed y, [row][hidden])
// ws (floats): Wq 196608 | Wpt 32768 | Wlt 16384 ; byte 983040: double partials[2][64]
// ---------------------------------------------------------------------------

#define NBLK 64
#define F(x) ((float)(x))

static __device__ __forceinline__ float rlane(float v, int l) {
  return __int_as_float(__builtin_amdgcn_readlane(__float_as_int(v), (unsigned)l));
}

__global__ void prep_kernel(const float* __restrict__ Wih,
                            const float* __restrict__ Wp,
                            const float* __restrict__ Wl,
                            float* __restrict__ ws) {
  int i = blockIdx.x * blockDim.x + threadIdx.x;
  if (i < 196608) {
    int j = i & 3, cc = (i >> 2) % 768, kq = (i >> 2) / 768;
    ws[i] = Wih[cc * 257 + kq * 4 + j];
  } else if (i < 229376) {
    int ii = i - 196608; int hh = ii & 255, k = ii >> 8;
    ws[i] = Wp[hh * 128 + k];
  } else if (i < 245760) {
    int ii = i - 229376; int c = ii & 63, k = ii >> 6;
    ws[i] = Wl[c * 256 + k];
  }
}

#define PBUF(si, j, c) smem[(si)*6144 + (j)*256 + (c)]
#define KLDS(i, r, c)  smem[18432 + (i)*2048 + (r)*256 + (c)]
#define YLDS(r, c)     smem[32768 + (r)*256 + (c)]

// Partial gate dot-products for hidden hh over K-slice s (64 wide), 8 rows.
__device__ __forceinline__ void eval_gates(
    const float4* __restrict__ Wq4, int s, int hh, const float* __restrict__ ysr,
    float* __restrict__ aR, float* __restrict__ aZ, float* __restrict__ aN) {
#pragma unroll
  for (int r = 0; r < 8; ++r) { aR[r] = 0.f; aZ[r] = 0.f; aN[r] = 0.f; }
  const float4* pR = Wq4 + hh;
  const float4* pZ = Wq4 + 256 + hh;
  const float4* pN = Wq4 + 512 + hh;
#pragma unroll 4
  for (int kq = 0; kq < 16; ++kq) {
    const int kqg = s * 16 + kq;
    float4 wr = pR[(size_t)kqg * 768];
    float4 wz = pZ[(size_t)kqg * 768];
    float4 wn = pN[(size_t)kqg * 768];
#pragma unroll
    for (int j = 0; j < 4; ++j) {
      const int ln = kq * 4 + j;  // wave-uniform broadcast lane
      const float wrj = (j == 0) ? wr.x : (j == 1) ? wr.y : (j == 2) ? wr.z : wr.w;
      const float wzj = (j == 0) ? wz.x : (j == 1) ? wz.y : (j == 2) ? wz.z : wz.w;
      const float wnj = (j == 0) ? wn.x : (j == 1) ? wn.y : (j == 2) ? wn.z : wn.w;
#pragma unroll
      for (int r = 0; r < 8; ++r) {
        const float a = rlane(ysr[r], ln);
        aR[r] = fmaf(a, wrj, aR[r]);
        aZ[r] = fmaf(a, wzj, aZ[r]);
        aN[r] = fmaf(a, wnj, aN[r]);
      }
    }
  }
}

// Full f-eval: partial gates -> LDS combine -> nonlinearity -> k_lds[KIDX].
#define EVALSTORE(KIDX, TS)                                                    \
  do {                                                                         \
    float aR[8], aZ[8], aN[8];                                                 \
    eval_gates(Wq4, s, hh, ys, aR, aZ, aN);                                    \
    if (s) {                                                                   \
      const int si = s - 1;                                                    \
      _Pragma("unroll") for (int r = 0; r < 8; ++r) {                          \
        PBUF(si, r, hh) = aR[r];                                               \
        PBUF(si, 8 + r, hh) = aZ[r];                                           \
        PBUF(si, 16 + r, hh) = aN[r];                                          \
      }                                                                        \
    }                                                                          \
    __syncthreads();                                                           \
    if (s == 0) {                                                              \
      const float ts_ = (TS);                                                  \
      const float cR = fmaf(ts_, wtR, bihR);                                   \
      const float cZ = fmaf(ts_, wtZ, bihZ);                                   \
      const float cN = fmaf(ts_, wtN, bihN);                                   \
      _Pragma("unroll") for (int r = 0; r < 8; ++r) {                          \
        float gR = ((aR[r] + PBUF(0, r, hh)) + PBUF(1, r, hh)) + PBUF(2, r, hh) + cR; \
        float gZ = ((aZ[r] + PBUF(0, 8 + r, hh)) + PBUF(1, 8 + r, hh)) + PBUF(2, 8 + r, hh) + cZ; \
        float gN = ((aN[r] + PBUF(0, 16 + r, hh)) + PBUF(1, 16 + r, hh)) + PBUF(2, 16 + r, hh) + cN; \
        const float rg_ = 1.0f / (1.0f + expf(-(gR + br_)));                   \
        const float zg_ = 1.0f / (1.0f + expf(-(gZ + bz_)));                   \
        const float ng_ = tanhf(gN + rg_ * bn_);                               \
        KLDS(KIDX, r, hh) = (1.0f - zg_) * ng_;                                \
      }                                                                        \
    }                                                                          \
    __syncthreads();                                                           \
  } while (0)

__global__ void __launch_bounds__(1024)
ode_kernel(const float* __restrict__ x,
           const float* __restrict__ tp, int nt,
           const float* __restrict__ bp,
           const float* __restrict__ Wih,
           const float* __restrict__ bih,
           const float* __restrict__ bhh,
           const float* __restrict__ bl,
           const float* __restrict__ ws_f,
           double* __restrict__ partials,
           float* __restrict__ out) {
  extern __shared__ float smem[];
  __shared__ double wred[16];
  __shared__ double s_b;
  cg::grid_group grid = cg::this_grid();

  const int rg = blockIdx.x;      // rows rg*8 .. rg*8+7
  const int t = threadIdx.x;
  const int s = t >> 8;           // K-slice 0..3
  const int hh = t & 255;         // hidden/gate index
  const int lane = t & 63;
  const int wv = t >> 6;
  const int sl = (s << 6) + lane; // hidden index this lane's y-slice regs hold

  const float4* Wq4 = (const float4*)ws_f;
  const float* Wpt = ws_f + 196608;
  const float* Wlt = ws_f + 229376;

  const float t0 = tp[0];
  const float t1v = tp[nt - 1];

  const float br_ = bhh[hh], bz_ = bhh[256 + hh], bn_ = bhh[512 + hh];
  const float bihR = bih[hh], bihZ = bih[256 + hh], bihN = bih[512 + hh];
  const float wtR = Wih[hh * 257 + 256];
  const float wtZ = Wih[(256 + hh) * 257 + 256];
  const float wtN = Wih[(512 + hh) * 257 + 256];

  // ---- h0 = x @ Wp.T + bp  (8 rows; xl aliases pbuf region) ----
  smem[t] = x[(rg * 8 + (t >> 7)) * 128 + (t & 127)];
  __syncthreads();
  if (s == 0) {
    float acc[8] = {0.f, 0.f, 0.f, 0.f, 0.f, 0.f, 0.f, 0.f};
    for (int k = 0; k < 128; ++k) {
      const float wv_ = Wpt[k * 256 + hh];
#pragma unroll
      for (int r = 0; r < 8; ++r) acc[r] = fmaf(smem[r * 128 + k], wv_, acc[r]);
    }
    const float bpv = bp[hh];
#pragma unroll
    for (int r = 0; r < 8; ++r) YLDS(r, hh) = acc[r] + bpv;
  }
  __syncthreads();

  float yb[8], ys[8];
#pragma unroll
  for (int r = 0; r < 8; ++r) { yb[r] = YLDS(r, sl); ys[r] = yb[r]; }

  float tcur = t0;
  float dt = (t1v - t0) * 0.01f + 1e-8f;

  EVALSTORE(0, t0);  // k1; FSAL afterwards

  for (int step = 0; step < 64; ++step) {
    if (t1v - tcur <= 1e-6f) break;  // exact: ref freezes state once done
    const float dtc = fminf(dt, t1v - tcur);

    // k2 @ t + 0.2 dt
#pragma unroll
    for (int r = 0; r < 8; ++r)
      ys[r] = fmaf(dtc * 0.2f, KLDS(0, r, sl), yb[r]);
    EVALSTORE(1, tcur + dtc * 0.2f);

    // k3 @ t + 0.3 dt
#pragma unroll
    for (int r = 0; r < 8; ++r)
      ys[r] = fmaf(dtc, fmaf(F(9.0 / 40.0), KLDS(1, r, sl),
                             F(3.0 / 40.0) * KLDS(0, r, sl)), yb[r]);
    EVALSTORE(2, tcur + dtc * 0.3f);

    // k4 @ t + 0.8 dt
#pragma unroll
    for (int r = 0; r < 8; ++r) {
      float in_ = F(44.0 / 45.0) * KLDS(0, r, sl);
      in_ = fmaf(F(-56.0 / 15.0), KLDS(1, r, sl), in_);
      in_ = fmaf(F(32.0 / 9.0), KLDS(2, r, sl), in_);
      ys[r] = fmaf(dtc, in_, yb[r]);
    }
    EVALSTORE(3, tcur + dtc * 0.8f);

    // k5 @ t + (8/9) dt
#pragma unroll
    for (int r = 0; r < 8; ++r) {
      float in_ = F(19372.0 / 6561.0) * KLDS(0, r, sl);
      in_ = fmaf(F(-25360.0 / 2187.0), KLDS(1, r, sl), in_);
      in_ = fmaf(F(64448.0 / 6561.0), KLDS(2, r, sl), in_);
      in_ = fmaf(F(-212.0 / 729.0), KLDS(3, r, sl), in_);
      ys[r] = fmaf(dtc, in_, yb[r]);
    }
    EVALSTORE(4, tcur + dtc * F(8.0 / 9.0));

    // k6 @ t + dt
#pragma unroll
    for (int r = 0; r < 8; ++r) {
      float in_ = F(9017.0 / 3168.0) * KLDS(0, r, sl);
      in_ = fmaf(F(-355.0 / 33.0), KLDS(1, r, sl), in_);
      in_ = fmaf(F(46732.0 / 5247.0), KLDS(2, r, sl), in_);
      in_ = fmaf(F(49.0 / 176.0), KLDS(3, r, sl), in_);
      in_ = fmaf(F(-5103.0 / 18656.0), KLDS(4, r, sl), in_);
      ys[r] = fmaf(dtc, in_, yb[r]);
    }
    EVALSTORE(5, tcur + dtc);

    // y5, then k7 = f(t+dt, y5)
#pragma unroll
    for (int r = 0; r < 8; ++r) {
      float in_ = F(35.0 / 384.0) * KLDS(0, r, sl);
      in_ = fmaf(F(500.0 / 1113.0), KLDS(2, r, sl), in_);
      in_ = fmaf(F(125.0 / 192.0), KLDS(3, r, sl), in_);
      in_ = fmaf(F(-2187.0 / 6784.0), KLDS(4, r, sl), in_);
      in_ = fmaf(F(11.0 / 84.0), KLDS(5, r, sl), in_);
      ys[r] = fmaf(dtc, in_, yb[r]);  // ys = y5 (kept through EVALSTORE)
    }
    EVALSTORE(6, tcur + dtc);

    // ---- error estimate (s==0 threads own elements (hh, 8 rows)) ----
    double lsum = 0.0;
    float y5s[8];
    if (s == 0) {
#pragma unroll
      for (int r = 0; r < 8; ++r) {
        const float k1v = KLDS(0, r, hh), k3v = KLDS(2, r, hh),
                    k4v = KLDS(3, r, hh), k5v = KLDS(4, r, hh),
                    k6v = KLDS(5, r, hh), k7v = KLDS(6, r, hh);
        const float yv = YLDS(r, hh);
        float in_ = F(35.0 / 384.0) * k1v;   // identical expr to lane y5
        in_ = fmaf(F(500.0 / 1113.0), k3v, in_);
        in_ = fmaf(F(125.0 / 192.0), k4v, in_);
        in_ = fmaf(F(-2187.0 / 6784.0), k5v, in_);
        in_ = fmaf(F(11.0 / 84.0), k6v, in_);
        const float y5v = fmaf(dtc, in_, yv);
        y5s[r] = y5v;
        float ev = F(71.0 / 57600.0) * k1v;
        ev = fmaf(F(-71.0 / 16695.0), k3v, ev);
        ev = fmaf(F(71.0 / 1920.0), k4v, ev);
        ev = fmaf(F(-17253.0 / 339200.0), k5v, ev);
        ev = fmaf(F(22.0 / 525.0), k6v, ev);
        ev = fmaf(F(-1.0 / 40.0), k7v, ev);
        ev *= dtc;
        const float sc = 1e-6f + 1e-5f * fmaxf(fabsf(yv), fabsf(y5v));
        const float qq = ev / sc;
        lsum += (double)(qq * qq);
      }
    }
    // wave butterfly -> per-wave -> block partial
    double v = lsum;
#pragma unroll
    for (int d = 1; d < 64; d <<= 1) v += __shfl_xor(v, d, 64);
    if (lane == 0) wred[wv] = v;
    __syncthreads();
    if (wv == 0) {
      double v2 = (lane < 16) ? wred[lane] : 0.0;
#pragma unroll
      for (int d = 1; d < 64; d <<= 1) v2 += __shfl_xor(v2, d, 64);
      if (lane == 0) partials[(step & 1) * NBLK + rg] = v2;
    }
    grid.sync();
    if (wv == 0) {
      double v3 = partials[(step & 1) * NBLK + lane];  // NBLK==64 lanes
#pragma unroll
      for (int d = 1; d < 64; d <<= 1) v3 += __shfl_xor(v3, d, 64);
      if (lane == 0) s_b = v3;
    }
    __syncthreads();
    const float err_norm = sqrtf((float)(s_b / 131072.0));
    const bool accept = (err_norm <= 1.0f);
    float factor = 0.9f * powf(err_norm + 1e-10f, -0.2f);
    factor = fminf(10.0f, fmaxf(0.2f, factor));
    if (accept) {
      tcur = tcur + dtc;
#pragma unroll
      for (int r = 0; r < 8; ++r) yb[r] = ys[r];  // ys == y5 per-lane
      if (s == 0) {
#pragma unroll
        for (int r = 0; r < 8; ++r) YLDS(r, hh) = y5s[r];
      }
      // FSAL: k1 <- k7 (flat copy, 2 elems/thread)
      smem[18432 + t] = smem[18432 + 6 * 2048 + t];
      smem[18432 + 1024 + t] = smem[18432 + 6 * 2048 + 1024 + t];
    }
    dt = dtc * factor;
    __syncthreads();
  }

  // ---- out = y @ Wl.T + bl ----
  __syncthreads();
  if (t < 512) {
    const int row = t >> 6, col = t & 63;
    float acc = bl[col];
    for (int k = 0; k < 256; ++k)
      acc = fmaf(YLDS(row, k), Wlt[k * 64 + col], acc);
    out[(rg * 8 + row) * 64 + col] = acc;
  }
}

extern "C" void kernel_launch(void* const* d_in, const int* in_sizes, int n_in,
                              void* d_out, int out_size, void* d_ws, size_t ws_size,
                              hipStream_t stream) {
  const float* x   = (const float*)d_in[0];
  const float* tp  = (const float*)d_in[1];
  const float* Wp  = (const float*)d_in[2];
  const float* bp  = (const float*)d_in[3];
  const float* Wih = (const float*)d_in[4];
  const float* bih = (const float*)d_in[5];
  const float* bhh = (const float*)d_in[7];
  const float* Wl  = (const float*)d_in[8];
  const float* bl  = (const float*)d_in[9];
  float* out = (float*)d_out;
  float* ws_f = (float*)d_ws;
  double* partials = (double*)((char*)d_ws + 983040);
  int nt = in_sizes[1];

  hipLaunchKernelGGL(prep_kernel, dim3(960), dim3(256), 0, stream, Wih, Wp, Wl, ws_f);

  const size_t shbytes = 34816 * sizeof(float);  // 136 KB dynamic LDS
  hipFuncSetAttribute((const void*)ode_kernel,
                      hipFuncAttributeMaxDynamicSharedMemorySize, (int)shbytes);

  void* args[] = { (void*)&x, (void*)&tp, (void*)&nt, (void*)&bp, (void*)&Wih,
                   (void*)&bih, (void*)&bhh, (void*)&bl, (void*)&ws_f,
                   (void*)&partials, (void*)&out };
  hipLaunchCooperativeKernel((void*)ode_kernel, dim3(NBLK), dim3(1024), args,
                             shbytes, stream);
}

// Round 3
// 772.151 us; speedup vs baseline: 1.4340x; 1.4340x over previous
//
#include <hip/hip_runtime.h>
#include <hip/hip_cooperative_groups.h>
#include <math.h>

namespace cg = cooperative_groups;

// ---------------------------------------------------------------------------
// Round 2: split-bf16 MFMA formulation.
//  - 32 blocks x 1024 threads (16 waves = 4/SIMD). Block owns 16 batch rows
//    (= M of one 16x16x32 MFMA tile). N=768 gate outputs: 48 n-tiles, 3/wave.
//  - Per f-eval: pack ys into A-fragments (bf16 hi+lo) in LDS; GEMM
//    acc = yl*Wh + yh*Wl + yh*Wh (fp32 MFMA accum, ~1e-5 rel accuracy);
//    gates g -> LDS (stride 772, conflict-free); elementwise GRU per thread
//    (4 owned elements), k-history entirely in registers.
//  - A and B fragments packed with the SAME k-permutation (k=(l>>4)*8+j),
//    so the MFMA k-pairing is consistent regardless of HW's internal order.
//    C/D mapping: col=lane&15, row=(lane>>4)*4+reg (HW-verified).
//  - Controller identical fp32 formula sequence to round 0/1 (passed).
//    FSAL, early exit, deterministic 2-level reduction, 1 grid.sync/step.
//
// ws layout (bytes):
//   [0,393216)        Wb_hi  ushort[196608]  B-frag-packed bf16 hi of Wih[:, :256]
//   [393216,786432)   Wb_lo  ushort[196608]  bf16 lo
//   [786432,917504)   Wpt    float[32768]    Wp transpose
//   [917504,983040)   Wlt    float[16384]    Wl transpose
//   [983040,983552)   partials double[2][32]
// Dynamic LDS (floats):
//   [0,12352)   g[16][772]  (gates; aliased: x-staging at init, y at end)
//   [12352)     yfrag_hi (4096 ushort), [14400) yfrag_lo (4096 ushort)
//   [16448..)   per-h consts: cR0,cZ0,bN,wtR,wtZ,wtN,bhN  (7 x 256 f32)
//   [18240)     wred double[16], [18272) s_b double
// ---------------------------------------------------------------------------

typedef __attribute__((ext_vector_type(8))) short bf16x8s;
typedef __attribute__((ext_vector_type(4))) float f32x4;

#define NBLK 32
#define GSTR 772
#define YHF 12352
#define YLF 14400
#define CR0F 16448
#define CZ0F 16704
#define BNF 16960
#define WTRF 17216
#define WTZF 17472
#define WTNF 17728
#define BHNF 17984
#define REDF 18240
#define SBF 18272
#define F(x) ((float)(x))

static __device__ __forceinline__ unsigned short f2bf(float f) {
  unsigned u = __float_as_uint(f);
  unsigned r = (u + 0x7FFFu + ((u >> 16) & 1u)) >> 16;
  return (unsigned short)r;
}
static __device__ __forceinline__ float bf2f(unsigned short b) {
  return __uint_as_float(((unsigned)b) << 16);
}
static __device__ __forceinline__ float sigm(float x) {
  return 1.0f / (1.0f + __expf(-x));
}
static __device__ __forceinline__ float tanh_fast(float x) {
  float e = __expf(-2.0f * fabsf(x));
  float t = (1.0f - e) / (1.0f + e);
  return copysignf(t, x);
}

__global__ void prep_kernel(const float* __restrict__ Wih,
                            const float* __restrict__ Wp,
                            const float* __restrict__ Wl,
                            float* __restrict__ ws) {
  int i = blockIdx.x * blockDim.x + threadIdx.x;
  if (i < 196608) {
    // B-fragment pack: j=i&7, l=(i>>3)&63, ks=(i>>9)&7, nt=i>>12
    const int j = i & 7, l = (i >> 3) & 63, ks = (i >> 9) & 7, nt = i >> 12;
    const int c = nt * 16 + (l & 15);          // gate-output column
    const int k = ks * 32 + (l >> 4) * 8 + j;  // k index (same perm as A)
    const float f = Wih[c * 257 + k];
    unsigned short hi = f2bf(f);
    unsigned short lo = f2bf(f - bf2f(hi));
    ((unsigned short*)ws)[i] = hi;
    ((unsigned short*)ws)[196608 + i] = lo;
  } else if (i < 229376) {
    int ii = i - 196608; int hh = ii & 255, k = ii >> 8;
    ws[i] = Wp[hh * 128 + k];
  } else if (i < 245760) {
    int ii = i - 229376; int c = ii & 63, k = ii >> 6;
    ws[i] = Wl[c * 256 + k];
  }
}

// One f-eval: ys (4 thread-owned elems) -> kout (4 elems). Uses LDS + MFMA.
__device__ __forceinline__ void eval_f(
    float* __restrict__ smem,
    const unsigned short* __restrict__ wbh,
    const unsigned short* __restrict__ wbl,
    int lane, int row, int h0, int fo, int nt0,
    const float ys[4], float ts_, float kout[4]) {
  // ---- pack ys -> A-frags (bf16 hi/lo), consistent k-perm ----
  unsigned short h_[4], l_[4];
#pragma unroll
  for (int c = 0; c < 4; ++c) {
    h_[c] = f2bf(ys[c]);
    l_[c] = f2bf(ys[c] - bf2f(h_[c]));
  }
  *(ushort4*)((unsigned short*)(smem + YHF) + fo) =
      make_ushort4(h_[0], h_[1], h_[2], h_[3]);
  *(ushort4*)((unsigned short*)(smem + YLF) + fo) =
      make_ushort4(l_[0], l_[1], l_[2], l_[3]);
  __syncthreads();

  // ---- GEMM: 3 n-tiles per wave, K=256 in 8 steps, 3 split-products ----
  f32x4 ac0 = {0.f, 0.f, 0.f, 0.f};
  f32x4 ac1 = {0.f, 0.f, 0.f, 0.f};
  f32x4 ac2 = {0.f, 0.f, 0.f, 0.f};
  const unsigned short* yh = (const unsigned short*)(smem + YHF);
  const unsigned short* yl = (const unsigned short*)(smem + YLF);
#pragma unroll
  for (int ks2 = 0; ks2 < 8; ++ks2) {
    const bf16x8s ah = *(const bf16x8s*)(yh + (ks2 * 64 + lane) * 8);
    const bf16x8s al = *(const bf16x8s*)(yl + (ks2 * 64 + lane) * 8);
    const bf16x8s bh0 = *(const bf16x8s*)(wbh + (((nt0 + 0) * 8 + ks2) * 64 + lane) * 8);
    const bf16x8s bl0 = *(const bf16x8s*)(wbl + (((nt0 + 0) * 8 + ks2) * 64 + lane) * 8);
    const bf16x8s bh1 = *(const bf16x8s*)(wbh + (((nt0 + 1) * 8 + ks2) * 64 + lane) * 8);
    const bf16x8s bl1 = *(const bf16x8s*)(wbl + (((nt0 + 1) * 8 + ks2) * 64 + lane) * 8);
    const bf16x8s bh2 = *(const bf16x8s*)(wbh + (((nt0 + 2) * 8 + ks2) * 64 + lane) * 8);
    const bf16x8s bl2 = *(const bf16x8s*)(wbl + (((nt0 + 2) * 8 + ks2) * 64 + lane) * 8);
    ac0 = __builtin_amdgcn_mfma_f32_16x16x32_bf16(al, bh0, ac0, 0, 0, 0);
    ac0 = __builtin_amdgcn_mfma_f32_16x16x32_bf16(ah, bl0, ac0, 0, 0, 0);
    ac0 = __builtin_amdgcn_mfma_f32_16x16x32_bf16(ah, bh0, ac0, 0, 0, 0);
    ac1 = __builtin_amdgcn_mfma_f32_16x16x32_bf16(al, bh1, ac1, 0, 0, 0);
    ac1 = __builtin_amdgcn_mfma_f32_16x16x32_bf16(ah, bl1, ac1, 0, 0, 0);
    ac1 = __builtin_amdgcn_mfma_f32_16x16x32_bf16(ah, bh1, ac1, 0, 0, 0);
    ac2 = __builtin_amdgcn_mfma_f32_16x16x32_bf16(al, bh2, ac2, 0, 0, 0);
    ac2 = __builtin_amdgcn_mfma_f32_16x16x32_bf16(ah, bl2, ac2, 0, 0, 0);
    ac2 = __builtin_amdgcn_mfma_f32_16x16x32_bf16(ah, bh2, ac2, 0, 0, 0);
  }
  // ---- C write: col=lane&15, row=(lane>>4)*4+j (HW-verified mapping) ----
  {
    const int gcol = lane & 15;
    const int gr0 = (lane >> 4) * 4;
#pragma unroll
    for (int j = 0; j < 4; ++j) {
      smem[(gr0 + j) * GSTR + (nt0 + 0) * 16 + gcol] = ac0[j];
      smem[(gr0 + j) * GSTR + (nt0 + 1) * 16 + gcol] = ac1[j];
      smem[(gr0 + j) * GSTR + (nt0 + 2) * 16 + gcol] = ac2[j];
    }
  }
  __syncthreads();

  // ---- GRU nonlinearity for thread-owned elements (row, h0..h0+3) ----
  float gRa[4], gZa[4], gNa[4], cra[4], cza[4], bna[4], wra[4], wza[4], wna[4], bha[4];
  {
    float4 tv;
    tv = *(const float4*)(smem + row * GSTR + h0);       gRa[0]=tv.x; gRa[1]=tv.y; gRa[2]=tv.z; gRa[3]=tv.w;
    tv = *(const float4*)(smem + row * GSTR + 256 + h0); gZa[0]=tv.x; gZa[1]=tv.y; gZa[2]=tv.z; gZa[3]=tv.w;
    tv = *(const float4*)(smem + row * GSTR + 512 + h0); gNa[0]=tv.x; gNa[1]=tv.y; gNa[2]=tv.z; gNa[3]=tv.w;
    tv = *(const float4*)(smem + CR0F + h0); cra[0]=tv.x; cra[1]=tv.y; cra[2]=tv.z; cra[3]=tv.w;
    tv = *(const float4*)(smem + CZ0F + h0); cza[0]=tv.x; cza[1]=tv.y; cza[2]=tv.z; cza[3]=tv.w;
    tv = *(const float4*)(smem + BNF + h0);  bna[0]=tv.x; bna[1]=tv.y; bna[2]=tv.z; bna[3]=tv.w;
    tv = *(const float4*)(smem + WTRF + h0); wra[0]=tv.x; wra[1]=tv.y; wra[2]=tv.z; wra[3]=tv.w;
    tv = *(const float4*)(smem + WTZF + h0); wza[0]=tv.x; wza[1]=tv.y; wza[2]=tv.z; wza[3]=tv.w;
    tv = *(const float4*)(smem + WTNF + h0); wna[0]=tv.x; wna[1]=tv.y; wna[2]=tv.z; wna[3]=tv.w;
    tv = *(const float4*)(smem + BHNF + h0); bha[0]=tv.x; bha[1]=tv.y; bha[2]=tv.z; bha[3]=tv.w;
  }
#pragma unroll
  for (int c = 0; c < 4; ++c) {
    const float rv = sigm(gRa[c] + cra[c] + ts_ * wra[c]);
    const float zv = sigm(gZa[c] + cza[c] + ts_ * wza[c]);
    const float nv = tanh_fast(gNa[c] + bna[c] + ts_ * wna[c] + rv * bha[c]);
    kout[c] = (1.0f - zv) * nv;
  }
}

__global__ void __launch_bounds__(1024)
ode_kernel(const float* __restrict__ x,
           const float* __restrict__ tp, int nt,
           const float* __restrict__ bp,
           const float* __restrict__ Wih,
           const float* __restrict__ bih,
           const float* __restrict__ bhh,
           const float* __restrict__ bl,
           const float* __restrict__ ws_f,
           double* __restrict__ partials,
           float* __restrict__ out) {
  extern __shared__ float smem[];
  cg::grid_group grid = cg::this_grid();

  const int rg = blockIdx.x;          // rows rg*16 .. rg*16+15
  const int t = threadIdx.x;
  const int lane = t & 63;
  const int w = t >> 6;               // wave = owned row
  const int row = w;
  const int h0 = lane * 4;            // owned hidden indices h0..h0+3
  const int nt0 = w * 3;              // this wave's 3 n-tiles
  const int fo = ((h0 >> 5) * 64 + row + ((h0 >> 3) & 3) * 16) * 8 + (h0 & 7);

  const unsigned short* wbh = (const unsigned short*)ws_f;
  const unsigned short* wbl = ((const unsigned short*)ws_f) + 196608;
  const float* Wpt = ws_f + 196608;
  const float* Wlt = ws_f + 229376;

  const float t0 = tp[0];
  const float t1v = tp[nt - 1];

  // ---- stage per-h constants into LDS ----
  if (t < 256) {
    smem[CR0F + t] = bih[t] + bhh[t];
    smem[CZ0F + t] = bih[256 + t] + bhh[256 + t];
    smem[BNF + t]  = bih[512 + t];
    smem[BHNF + t] = bhh[512 + t];
    smem[WTRF + t] = Wih[t * 257 + 256];
    smem[WTZF + t] = Wih[(256 + t) * 257 + 256];
    smem[WTNF + t] = Wih[(512 + t) * 257 + 256];
  }
  // ---- stage x (16 rows x 128) into g area ----
  smem[t] = x[(rg * 16 + (t >> 7)) * 128 + (t & 127)];
  {
    const int i2 = t + 1024;
    smem[i2] = x[(rg * 16 + (i2 >> 7)) * 128 + (i2 & 127)];
  }
  __syncthreads();

  // ---- h0 = x @ Wp.T + bp (fp32 VALU, once) ----
  float yb[4];
  {
    float acc[4] = {0.f, 0.f, 0.f, 0.f};
    for (int k = 0; k < 128; ++k) {
      const float xv = smem[row * 128 + k];
      const float4 wv4 = *(const float4*)(Wpt + k * 256 + h0);
      acc[0] = fmaf(xv, wv4.x, acc[0]);
      acc[1] = fmaf(xv, wv4.y, acc[1]);
      acc[2] = fmaf(xv, wv4.z, acc[2]);
      acc[3] = fmaf(xv, wv4.w, acc[3]);
    }
    const float4 bp4 = *(const float4*)(bp + h0);
    yb[0] = acc[0] + bp4.x; yb[1] = acc[1] + bp4.y;
    yb[2] = acc[2] + bp4.z; yb[3] = acc[3] + bp4.w;
  }

  float tcur = t0;
  float dt = (t1v - t0) * 0.01f + 1e-8f;

  float k1v[4], k2v[4], k3v[4], k4v[4], k5v[4], k6v[4], k7v[4];
  float ys[4];

#pragma unroll
  for (int c = 0; c < 4; ++c) ys[c] = yb[c];
  eval_f(smem, wbh, wbl, lane, row, h0, fo, nt0, ys, t0, k1v);  // k1; FSAL after

  for (int step = 0; step < 64; ++step) {
    if (t1v - tcur <= 1e-6f) break;  // exact: ref freezes state once done
    const float dtc = fminf(dt, t1v - tcur);

#pragma unroll
    for (int c = 0; c < 4; ++c) ys[c] = fmaf(dtc * 0.2f, k1v[c], yb[c]);
    eval_f(smem, wbh, wbl, lane, row, h0, fo, nt0, ys, tcur + dtc * 0.2f, k2v);

#pragma unroll
    for (int c = 0; c < 4; ++c)
      ys[c] = fmaf(dtc, fmaf(F(9.0/40.0), k2v[c], F(3.0/40.0) * k1v[c]), yb[c]);
    eval_f(smem, wbh, wbl, lane, row, h0, fo, nt0, ys, tcur + dtc * 0.3f, k3v);

#pragma unroll
    for (int c = 0; c < 4; ++c) {
      float in_ = F(44.0/45.0) * k1v[c];
      in_ = fmaf(F(-56.0/15.0), k2v[c], in_);
      in_ = fmaf(F(32.0/9.0), k3v[c], in_);
      ys[c] = fmaf(dtc, in_, yb[c]);
    }
    eval_f(smem, wbh, wbl, lane, row, h0, fo, nt0, ys, tcur + dtc * 0.8f, k4v);

#pragma unroll
    for (int c = 0; c < 4; ++c) {
      float in_ = F(19372.0/6561.0) * k1v[c];
      in_ = fmaf(F(-25360.0/2187.0), k2v[c], in_);
      in_ = fmaf(F(64448.0/6561.0), k3v[c], in_);
      in_ = fmaf(F(-212.0/729.0), k4v[c], in_);
      ys[c] = fmaf(dtc, in_, yb[c]);
    }
    eval_f(smem, wbh, wbl, lane, row, h0, fo, nt0, ys, tcur + dtc * F(8.0/9.0), k5v);

#pragma unroll
    for (int c = 0; c < 4; ++c) {
      float in_ = F(9017.0/3168.0) * k1v[c];
      in_ = fmaf(F(-355.0/33.0), k2v[c], in_);
      in_ = fmaf(F(46732.0/5247.0), k3v[c], in_);
      in_ = fmaf(F(49.0/176.0), k4v[c], in_);
      in_ = fmaf(F(-5103.0/18656.0), k5v[c], in_);
      ys[c] = fmaf(dtc, in_, yb[c]);
    }
    eval_f(smem, wbh, wbl, lane, row, h0, fo, nt0, ys, tcur + dtc, k6v);

    // y5 into ys, k7 = f(t+dt, y5)
#pragma unroll
    for (int c = 0; c < 4; ++c) {
      float in_ = F(35.0/384.0) * k1v[c];
      in_ = fmaf(F(500.0/1113.0), k3v[c], in_);
      in_ = fmaf(F(125.0/192.0), k4v[c], in_);
      in_ = fmaf(F(-2187.0/6784.0), k5v[c], in_);
      in_ = fmaf(F(11.0/84.0), k6v[c], in_);
      ys[c] = fmaf(dtc, in_, yb[c]);
    }
    eval_f(smem, wbh, wbl, lane, row, h0, fo, nt0, ys, tcur + dtc, k7v);

    // ---- error estimate over thread-owned elements ----
    double lsum = 0.0;
#pragma unroll
    for (int c = 0; c < 4; ++c) {
      float ev = F(71.0/57600.0) * k1v[c];
      ev = fmaf(F(-71.0/16695.0), k3v[c], ev);
      ev = fmaf(F(71.0/1920.0), k4v[c], ev);
      ev = fmaf(F(-17253.0/339200.0), k5v[c], ev);
      ev = fmaf(F(22.0/525.0), k6v[c], ev);
      ev = fmaf(F(-1.0/40.0), k7v[c], ev);
      ev *= dtc;
      const float sc = 1e-6f + 1e-5f * fmaxf(fabsf(yb[c]), fabsf(ys[c]));
      const float qq = ev / sc;
      lsum += (double)(qq * qq);
    }
    // wave butterfly -> per-wave -> block partial -> grid -> broadcast
    double v = lsum;
#pragma unroll
    for (int d = 1; d < 64; d <<= 1) v += __shfl_xor(v, d, 64);
    if (lane == 0) ((double*)(smem + REDF))[w] = v;
    __syncthreads();
    if (w == 0) {
      double v2 = (lane < 16) ? ((double*)(smem + REDF))[lane] : 0.0;
#pragma unroll
      for (int d = 1; d < 64; d <<= 1) v2 += __shfl_xor(v2, d, 64);
      if (lane == 0) partials[(step & 1) * NBLK + rg] = v2;
    }
    grid.sync();
    if (w == 0) {
      double v3 = (lane < NBLK) ? partials[(step & 1) * NBLK + lane] : 0.0;
#pragma unroll
      for (int d = 1; d < 64; d <<= 1) v3 += __shfl_xor(v3, d, 64);
      if (lane == 0) ((double*)(smem + SBF))[0] = v3;
    }
    __syncthreads();
    const double sb = ((double*)(smem + SBF))[0];
    const float err_norm = sqrtf((float)(sb / 131072.0));
    const bool accept = (err_norm <= 1.0f);
    float factor = 0.9f * powf(err_norm + 1e-10f, -0.2f);
    factor = fminf(10.0f, fmaxf(0.2f, factor));
    if (accept) {
      tcur = tcur + dtc;
#pragma unroll
      for (int c = 0; c < 4; ++c) { yb[c] = ys[c]; k1v[c] = k7v[c]; }  // FSAL
    }
    dt = dtc * factor;
  }

  // ---- out = y @ Wl.T + bl ----
  __syncthreads();
#pragma unroll
  for (int c = 0; c < 4; ++c) smem[row * 256 + h0 + c] = yb[c];
  __syncthreads();
  {
    const int orow = t >> 6, oc = t & 63;
    float acc = bl[oc];
    for (int k = 0; k < 256; ++k)
      acc = fmaf(smem[orow * 256 + k], Wlt[k * 64 + oc], acc);
    out[(rg * 16 + orow) * 64 + oc] = acc;
  }
}

extern "C" void kernel_launch(void* const* d_in, const int* in_sizes, int n_in,
                              void* d_out, int out_size, void* d_ws, size_t ws_size,
                              hipStream_t stream) {
  const float* x   = (const float*)d_in[0];
  const float* tp  = (const float*)d_in[1];
  const float* Wp  = (const float*)d_in[2];
  const float* bp  = (const float*)d_in[3];
  const float* Wih = (const float*)d_in[4];
  const float* bih = (const float*)d_in[5];
  const float* bhh = (const float*)d_in[7];
  const float* Wl  = (const float*)d_in[8];
  const float* bl  = (const float*)d_in[9];
  float* out = (float*)d_out;
  float* ws_f = (float*)d_ws;
  double* partials = (double*)((char*)d_ws + 983040);
  int nt = in_sizes[1];

  hipLaunchKernelGGL(prep_kernel, dim3(960), dim3(256), 0, stream, Wih, Wp, Wl, ws_f);

  const size_t shbytes = 73216;  // 18274 floats rounded up
  hipFuncSetAttribute((const void*)ode_kernel,
                      hipFuncAttributeMaxDynamicSharedMemorySize, (int)shbytes);

  void* args[] = { (void*)&x, (void*)&tp, (void*)&nt, (void*)&bp, (void*)&Wih,
                   (void*)&bih, (void*)&bhh, (void*)&bl, (void*)&ws_f,
                   (void*)&partials, (void*)&out };
  hipLaunchCooperativeKernel((void*)ode_kernel, dim3(NBLK), dim3(1024), args,
                             shbytes, stream);
}